// Round 6
// baseline (461.921 us; speedup 1.0000x reference)
//
#include <hip/hip_runtime.h>
#include <hip/hip_bf16.h>
#include <cmath>

#define B_ 4
#define P_ 1024
#define KN_ 16
#define D_ 768
#define H_ 12
#define S_ 1025
#define NROWS (B_ * S_) // 4100

typedef __attribute__((ext_vector_type(8))) short short8;
typedef __attribute__((ext_vector_type(4))) float f32x4;

__device__ __forceinline__ float bf2f(short u) {
  return __uint_as_float(((unsigned int)(unsigned short)u) << 16);
}

__device__ __forceinline__ float wave_reduce_sum(float v) {
#pragma unroll
  for (int off = 32; off > 0; off >>= 1) v += __shfl_xor(v, off);
  return v;
}

__device__ __forceinline__ void gload16(const void* g, void* l) {
  __builtin_amdgcn_global_load_lds(
      (const __attribute__((address_space(1))) unsigned int*)g,
      (__attribute__((address_space(3))) unsigned int*)l, 16, 0, 0);
}

// ---------------- LayerNorm over D=768 -> bf16 out ---------------------------
__global__ __launch_bounds__(256) void ln_bf16(const float* __restrict__ x,
                                               const float* __restrict__ g,
                                               const float* __restrict__ b,
                                               __hip_bfloat16* __restrict__ y) {
  const int row = blockIdx.x;
  const float* xr = x + (size_t)row * D_;
  __hip_bfloat16* yr = y + (size_t)row * D_;
  const int t = threadIdx.x;
  const float v0 = xr[t], v1 = xr[t + 256], v2 = xr[t + 512];
  float s = v0 + v1 + v2;
  float ss = v0 * v0 + v1 * v1 + v2 * v2;
  s = wave_reduce_sum(s);
  ss = wave_reduce_sum(ss);
  __shared__ float rs[4], rss[4];
  const int wid = t >> 6, lane = t & 63;
  if (lane == 0) { rs[wid] = s; rss[wid] = ss; }
  __syncthreads();
  const float tot = rs[0] + rs[1] + rs[2] + rs[3];
  const float tot2 = rss[0] + rss[1] + rss[2] + rss[3];
  const float mean = tot * (1.0f / D_);
  const float var = tot2 * (1.0f / D_) - mean * mean;
  const float rstd = rsqrtf(var + 1e-5f);
  yr[t]       = __float2bfloat16((v0 - mean) * rstd * g[t]       + b[t]);
  yr[t + 256] = __float2bfloat16((v1 - mean) * rstd * g[t + 256] + b[t + 256]);
  yr[t + 512] = __float2bfloat16((v2 - mean) * rstd * g[t + 512] + b[t + 512]);
}

// ---------------- weight transpose+convert: W[K][N] f32 -> WT[N][K] bf16 -----
__global__ __launch_bounds__(256) void wtrans(const float* __restrict__ W,
                                              __hip_bfloat16* __restrict__ WT,
                                              int K, int N) {
  __shared__ float t[32][33];
  const int tx = threadIdx.x & 31, ty = threadIdx.x >> 5; // 32 x 8
  const int n0 = blockIdx.x * 32, k0 = blockIdx.y * 32;
#pragma unroll
  for (int i = 0; i < 32; i += 8)
    t[ty + i][tx] = W[(size_t)(k0 + ty + i) * N + n0 + tx];
  __syncthreads();
#pragma unroll
  for (int i = 0; i < 32; i += 8)
    WT[(size_t)(n0 + ty + i) * K + k0 + tx] = __float2bfloat16(t[tx][ty + i]);
}

// ---------------- bf16 MFMA GEMM: C[MxN] = A[MxK] @ WT[NxK]^T + bias (+epi) --
// 128x128 tile, BK=32, 4 waves each 64x64 (4x4 frags of 16x16x32).
// Staging per rule 21: LINEAR LDS dest (wave-uniform base + lane*16B),
// inverse-swizzled global SOURCE chunk, matching XOR on the ds_read.
// Bank check: 16-lane group covers all 32 banks exactly 2x -> free (m136).
// EPI: 0 = bias -> bf16 out; 1 = bias+resid(f32) -> f32 out; 2 = bias+GELU -> bf16 out
template <int EPI>
__global__ __launch_bounds__(256) void gemm_mfma(
    const __hip_bfloat16* __restrict__ A, const __hip_bfloat16* __restrict__ WT,
    const float* __restrict__ bias, const float* __restrict__ resid,
    void* __restrict__ Cv, int M, int N, int K) {
  __shared__ __align__(16) __hip_bfloat16 As[128][32];
  __shared__ __align__(16) __hip_bfloat16 Bs[128][32];
  const int tid = threadIdx.x;
  const int l = tid & 63, w = tid >> 6;
  const int wr = w >> 1, wc = w & 1;
  const int m0 = blockIdx.y * 128, n0 = blockIdx.x * 128;

  f32x4 acc[4][4] = {};
  const int lrow = l & 15, lk = l >> 4;
  const int srow = l >> 2, schunk = l & 3;

  for (int k0 = 0; k0 < K; k0 += 32) {
#pragma unroll
    for (int q = 0; q < 2; ++q) {
      const int s = w * 2 + q;
      const int r = s * 16 + srow;                 // tile row this lane stages
      const int c = schunk ^ ((r >> 1) & 3);       // inverse-swizzled source chunk
      gload16(A  + (size_t)(m0 + r) * K + k0 + c * 8, &As[s * 16][0]);
      gload16(WT + (size_t)(n0 + r) * K + k0 + c * 8, &Bs[s * 16][0]);
    }
    __syncthreads();  // drains vmcnt before barrier (compiler-enforced)

    short8 af[4], bf[4];
#pragma unroll
    for (int i = 0; i < 4; ++i) {
      const int ra = wr * 64 + i * 16 + lrow;
      af[i] = *(const short8*)&As[ra][(lk ^ ((ra >> 1) & 3)) * 8];
      const int rb = wc * 64 + i * 16 + lrow;
      bf[i] = *(const short8*)&Bs[rb][(lk ^ ((rb >> 1) & 3)) * 8];
    }
#pragma unroll
    for (int i = 0; i < 4; ++i)
#pragma unroll
      for (int j = 0; j < 4; ++j)
        acc[i][j] = __builtin_amdgcn_mfma_f32_16x16x32_bf16(af[i], bf[j], acc[i][j], 0, 0, 0);
    __syncthreads();
  }

#pragma unroll
  for (int i = 0; i < 4; ++i) {
#pragma unroll
    for (int j = 0; j < 4; ++j) {
#pragma unroll
      for (int rg = 0; rg < 4; ++rg) {
        const int m = m0 + wr * 64 + i * 16 + (l >> 4) * 4 + rg;
        const int n = n0 + wc * 64 + j * 16 + (l & 15);
        if (m < M) {
          float v = acc[i][j][rg] + bias[n];
          if (EPI == 1) v += resid[(size_t)m * N + n];
          if (EPI == 2) v = 0.5f * v * (1.f + erff(v * 0.70710678118654752f));
          if (EPI == 1) ((float*)Cv)[(size_t)m * N + n] = v;
          else ((__hip_bfloat16*)Cv)[(size_t)m * N + n] = __float2bfloat16(v);
        }
      }
    }
  }
}

// ---------------- CLS attention (bf16 qkv in, bf16 out) ----------------------
__global__ __launch_bounds__(256) void attn_cls(const __hip_bfloat16* __restrict__ qkv,
                                                __hip_bfloat16* __restrict__ out) {
  const int b = blockIdx.x / H_, h = blockIdx.x % H_;
  __shared__ float qs[64];
  __shared__ float sc[S_];
  __shared__ float red[4];
  __shared__ float part[4][64];
  const int t = threadIdx.x;
  const int wid = t >> 6, lane = t & 63;
  const int rowbase = b * S_;
  if (t < 64) qs[t] = __bfloat162float(qkv[(size_t)rowbase * 2304 + h * 64 + t]);
  __syncthreads();

  float lmax = -1e30f;
  for (int k = t; k < S_; k += 256) {
    const short8* kp8 = (const short8*)(qkv + (size_t)(rowbase + k) * 2304 + 768 + h * 64);
    float d = 0.f;
#pragma unroll
    for (int i = 0; i < 8; ++i) {
      const short8 v = kp8[i];
#pragma unroll
      for (int j = 0; j < 8; ++j) d += qs[i * 8 + j] * bf2f(v[j]);
    }
    d *= 0.125f;
    sc[k] = d;
    lmax = fmaxf(lmax, d);
  }
#pragma unroll
  for (int off = 32; off > 0; off >>= 1) lmax = fmaxf(lmax, __shfl_xor(lmax, off));
  if (lane == 0) red[wid] = lmax;
  __syncthreads();
  const float mx = fmaxf(fmaxf(red[0], red[1]), fmaxf(red[2], red[3]));
  __syncthreads();

  float lsum = 0.f;
  for (int k = t; k < S_; k += 256) {
    const float e = expf(sc[k] - mx);
    sc[k] = e;
    lsum += e;
  }
  lsum = wave_reduce_sum(lsum);
  if (lane == 0) red[wid] = lsum;
  __syncthreads();
  const float den = red[0] + red[1] + red[2] + red[3];

  float acc = 0.f;
  for (int k = wid; k < S_; k += 4) {
    acc += sc[k] * __bfloat162float(qkv[(size_t)(rowbase + k) * 2304 + 1536 + h * 64 + lane]);
  }
  part[wid][lane] = acc;
  __syncthreads();
  if (t < 64) {
    const float o = (part[0][t] + part[1][t] + part[2][t] + part[3][t]) / den;
    out[(size_t)rowbase * 768 + h * 64 + t] = __float2bfloat16(o);
  }
}

// ---------------- Patch attention: one wave per (b,h,p), 16 routed keys ------
__global__ __launch_bounds__(256) void attn_patch(const __hip_bfloat16* __restrict__ qkv,
                                                  const int* __restrict__ routes,
                                                  __hip_bfloat16* __restrict__ out) {
  const int gwid = (int)((blockIdx.x * 256 + threadIdx.x) >> 6);
  const int lane = threadIdx.x & 63;
  const int p = gwid & (P_ - 1);
  const int bh = gwid >> 10;
  const int h = bh % H_, b = bh / H_;
  const int qrow = b * S_ + p + 1;
  const float q = __bfloat162float(qkv[(size_t)qrow * 2304 + h * 64 + lane]);

  int krow[KN_];
#pragma unroll
  for (int j = 0; j < KN_; ++j) krow[j] = b * S_ + routes[p * KN_ + j] + 1;

  float sc[KN_];
#pragma unroll
  for (int j = 0; j < KN_; ++j) {
    float d = q * __bfloat162float(qkv[(size_t)krow[j] * 2304 + 768 + h * 64 + lane]);
    d = wave_reduce_sum(d);
    sc[j] = d * 0.125f;
  }
  float mx = sc[0];
#pragma unroll
  for (int j = 1; j < KN_; ++j) mx = fmaxf(mx, sc[j]);
  float den = 0.f;
#pragma unroll
  for (int j = 0; j < KN_; ++j) { sc[j] = expf(sc[j] - mx); den += sc[j]; }
  const float inv = 1.f / den;
  float o = 0.f;
#pragma unroll
  for (int j = 0; j < KN_; ++j)
    o += sc[j] * __bfloat162float(qkv[(size_t)krow[j] * 2304 + 1536 + h * 64 + lane]);
  out[(size_t)qrow * 768 + h * 64 + lane] = __float2bfloat16(o * inv);
}

// ---------------- launcher ---------------------------------------------------
extern "C" void kernel_launch(void* const* d_in, const int* in_sizes, int n_in,
                              void* d_out, int out_size, void* d_ws, size_t ws_size,
                              hipStream_t stream) {
  const float* x      = (const float*)d_in[0];
  const int*   routes = (const int*)d_in[1];
  const float* qkv_w  = (const float*)d_in[2];
  const float* qkv_b  = (const float*)d_in[3];
  const float* proj_w = (const float*)d_in[4];
  const float* proj_b = (const float*)d_in[5];
  const float* ln1_g  = (const float*)d_in[6];
  const float* ln1_b  = (const float*)d_in[7];
  const float* ln2_g  = (const float*)d_in[8];
  const float* ln2_b  = (const float*)d_in[9];
  const float* mlp_w1 = (const float*)d_in[10];
  const float* mlp_b1 = (const float*)d_in[11];
  const float* mlp_w2 = (const float*)d_in[12];
  const float* mlp_b2 = (const float*)d_in[13];
  float* outp = (float*)d_out;

  // ws layout (bf16 unless noted). A-tile overreads on the last M-tile land
  // in the subsequent buffer (finite values, rows masked at C-write).
  __hip_bfloat16* xn    = (__hip_bfloat16*)d_ws;            // NROWS*768
  __hip_bfloat16* qkv   = xn + (size_t)NROWS * 768;         // NROWS*2304
  __hip_bfloat16* attn  = qkv + (size_t)NROWS * 2304;       // NROWS*768
  float*          x1    = (float*)(attn + (size_t)NROWS * 768); // NROWS*768 f32
  __hip_bfloat16* h1    = (__hip_bfloat16*)(x1 + (size_t)NROWS * 768); // NROWS*3072
  __hip_bfloat16* wqkvT = h1 + (size_t)NROWS * 3072;        // 2304*768
  __hip_bfloat16* wprojT= wqkvT + (size_t)2304 * 768;       // 768*768
  __hip_bfloat16* w1T   = wprojT + (size_t)768 * 768;       // 3072*768
  __hip_bfloat16* w2T   = w1T + (size_t)3072 * 768;         // 768*3072

  const int mt = (NROWS + 127) / 128; // 33

  // weight transpose+convert (f32 [K][N] -> bf16 [N][K])
  wtrans<<<dim3(2304 / 32, 768 / 32), 256, 0, stream>>>(qkv_w, wqkvT, 768, 2304);
  wtrans<<<dim3(768 / 32, 768 / 32), 256, 0, stream>>>(proj_w, wprojT, 768, 768);
  wtrans<<<dim3(3072 / 32, 768 / 32), 256, 0, stream>>>(mlp_w1, w1T, 768, 3072);
  wtrans<<<dim3(768 / 32, 3072 / 32), 256, 0, stream>>>(mlp_w2, w2T, 3072, 768);

  ln_bf16<<<NROWS, 256, 0, stream>>>(x, ln1_g, ln1_b, xn);
  gemm_mfma<0><<<dim3(2304 / 128, mt), 256, 0, stream>>>(
      xn, wqkvT, qkv_b, nullptr, qkv, NROWS, 2304, 768);
  attn_cls<<<B_ * H_, 256, 0, stream>>>(qkv, attn);
  attn_patch<<<B_ * H_ * P_ / 4, 256, 0, stream>>>(qkv, routes, attn);
  gemm_mfma<1><<<dim3(768 / 128, mt), 256, 0, stream>>>(
      attn, wprojT, proj_b, x, x1, NROWS, 768, 768);
  ln_bf16<<<NROWS, 256, 0, stream>>>(x1, ln2_g, ln2_b, xn);
  gemm_mfma<2><<<dim3(3072 / 128, mt), 256, 0, stream>>>(
      xn, w1T, mlp_b1, nullptr, h1, NROWS, 3072, 768);
  gemm_mfma<1><<<dim3(768 / 128, mt), 256, 0, stream>>>(
      h1, w2T, mlp_b2, x1, outp, NROWS, 768, 3072);
}

// Round 7
// 398.952 us; speedup vs baseline: 1.1578x; 1.1578x over previous
//
#include <hip/hip_runtime.h>
#include <hip/hip_bf16.h>
#include <cmath>

#define B_ 4
#define P_ 1024
#define KN_ 16
#define D_ 768
#define H_ 12
#define S_ 1025
#define NROWS (B_ * S_) // 4100

typedef __attribute__((ext_vector_type(8))) short short8;
typedef __attribute__((ext_vector_type(4))) float f32x4;

__device__ __forceinline__ float bf2f(short u) {
  return __uint_as_float(((unsigned int)(unsigned short)u) << 16);
}

__device__ __forceinline__ float wave_reduce_sum(float v) {
#pragma unroll
  for (int off = 32; off > 0; off >>= 1) v += __shfl_xor(v, off);
  return v;
}

__device__ __forceinline__ void gload16(const void* g, void* l) {
  __builtin_amdgcn_global_load_lds(
      (const __attribute__((address_space(1))) unsigned int*)g,
      (__attribute__((address_space(3))) unsigned int*)l, 16, 0, 0);
}

// ---------------- LayerNorm over D=768 -> bf16 out ---------------------------
__global__ __launch_bounds__(256) void ln_bf16(const float* __restrict__ x,
                                               const float* __restrict__ g,
                                               const float* __restrict__ b,
                                               __hip_bfloat16* __restrict__ y) {
  const int row = blockIdx.x;
  const float* xr = x + (size_t)row * D_;
  __hip_bfloat16* yr = y + (size_t)row * D_;
  const int t = threadIdx.x;
  const float v0 = xr[t], v1 = xr[t + 256], v2 = xr[t + 512];
  float s = v0 + v1 + v2;
  float ss = v0 * v0 + v1 * v1 + v2 * v2;
  s = wave_reduce_sum(s);
  ss = wave_reduce_sum(ss);
  __shared__ float rs[4], rss[4];
  const int wid = t >> 6, lane = t & 63;
  if (lane == 0) { rs[wid] = s; rss[wid] = ss; }
  __syncthreads();
  const float tot = rs[0] + rs[1] + rs[2] + rs[3];
  const float tot2 = rss[0] + rss[1] + rss[2] + rss[3];
  const float mean = tot * (1.0f / D_);
  const float var = tot2 * (1.0f / D_) - mean * mean;
  const float rstd = rsqrtf(var + 1e-5f);
  yr[t]       = __float2bfloat16((v0 - mean) * rstd * g[t]       + b[t]);
  yr[t + 256] = __float2bfloat16((v1 - mean) * rstd * g[t + 256] + b[t + 256]);
  yr[t + 512] = __float2bfloat16((v2 - mean) * rstd * g[t + 512] + b[t + 512]);
}

// ---------------- weight transpose+convert: W[K][N] f32 -> WT[N][K] bf16 -----
__global__ __launch_bounds__(256) void wtrans(const float* __restrict__ W,
                                              __hip_bfloat16* __restrict__ WT,
                                              int K, int N) {
  __shared__ float t[32][33];
  const int tx = threadIdx.x & 31, ty = threadIdx.x >> 5; // 32 x 8
  const int n0 = blockIdx.x * 32, k0 = blockIdx.y * 32;
#pragma unroll
  for (int i = 0; i < 32; i += 8)
    t[ty + i][tx] = W[(size_t)(k0 + ty + i) * N + n0 + tx];
  __syncthreads();
#pragma unroll
  for (int i = 0; i < 32; i += 8)
    WT[(size_t)(n0 + ty + i) * K + k0 + tx] = __float2bfloat16(t[tx][ty + i]);
}

// ---------------- bf16 MFMA GEMM: C[MxN] = A[MxK] @ WT[NxK]^T + bias (+epi) --
// BM=128, BN=64, BK=64. 4 waves, each 64x32 (4x2 frags of 16x16x32).
// Double-buffered (statically distinct As0/As1 so the compiler can
// disambiguate global_load_lds writes from ds_reads — no spurious vmcnt
// before MFMA). 2-phase pipeline: stage tile t+1 while computing tile t;
// the barrier's vmcnt(0) drain lands after 16 MFMAs (T3-minimum recipe).
// Swizzle (rule 21): LDS[row][c] = G[row][c ^ (row&7)], 16B chunks; linear
// LDS dest (wave-uniform base + lane*16), inverse-swizzled global source,
// matching XOR on ds_read. Read phase: 2 lanes/bank = free (m136).
// EPI: 0 = bias -> bf16 out; 1 = bias+resid(f32) -> f32 out; 2 = bias+GELU -> bf16 out
#define STAGE(AS, BS, kt)                                                      \
  {                                                                            \
    _Pragma("unroll")                                                          \
    for (int q = 0; q < 4; ++q)                                                \
      gload16(A + (size_t)(m0 + w * 32 + q * 8 + lrow8) * K + (kt) * 64 +      \
                  lchk * 8,                                                    \
              &AS[w * 32 + q * 8][0]);                                         \
    _Pragma("unroll")                                                          \
    for (int q = 0; q < 2; ++q)                                                \
      gload16(WT + (size_t)(n0 + w * 16 + q * 8 + lrow8) * K + (kt) * 64 +     \
                  lchk * 8,                                                    \
              &BS[w * 16 + q * 8][0]);                                         \
  }

#define COMPUTE(AS, BS)                                                        \
  {                                                                            \
    short8 af[4][2], bfr[2][2];                                                \
    _Pragma("unroll")                                                          \
    for (int i = 0; i < 4; ++i) {                                              \
      _Pragma("unroll")                                                        \
      for (int s = 0; s < 2; ++s) {                                            \
        const int ra = wr * 64 + i * 16 + fr;                                  \
        af[i][s] = *(const short8*)&AS[ra][((s * 4 + fk) ^ (ra & 7)) * 8];     \
      }                                                                        \
    }                                                                          \
    _Pragma("unroll")                                                          \
    for (int j = 0; j < 2; ++j) {                                              \
      _Pragma("unroll")                                                        \
      for (int s = 0; s < 2; ++s) {                                            \
        const int rb = wc * 32 + j * 16 + fr;                                  \
        bfr[j][s] = *(const short8*)&BS[rb][((s * 4 + fk) ^ (rb & 7)) * 8];    \
      }                                                                        \
    }                                                                          \
    _Pragma("unroll")                                                          \
    for (int i = 0; i < 4; ++i) {                                              \
      _Pragma("unroll")                                                        \
      for (int j = 0; j < 2; ++j) {                                            \
        _Pragma("unroll")                                                      \
        for (int s = 0; s < 2; ++s)                                            \
          acc[i][j] = __builtin_amdgcn_mfma_f32_16x16x32_bf16(                 \
              af[i][s], bfr[j][s], acc[i][j], 0, 0, 0);                        \
      }                                                                        \
    }                                                                          \
  }

template <int EPI>
__global__ __launch_bounds__(256) void gemm_mfma(
    const __hip_bfloat16* __restrict__ A, const __hip_bfloat16* __restrict__ WT,
    const float* __restrict__ bias, const float* __restrict__ resid,
    void* __restrict__ Cv, int M, int N, int K) {
  __shared__ __align__(16) __hip_bfloat16 As0[128][64], As1[128][64];
  __shared__ __align__(16) __hip_bfloat16 Bs0[64][64], Bs1[64][64];
  const int tid = threadIdx.x;
  const int l = tid & 63, w = tid >> 6;
  const int wr = w >> 1, wc = w & 1;     // wave-row (64), wave-col (32)
  const int fr = l & 15, fk = l >> 4;    // frag row / k-subchunk
  const int lrow8 = l >> 3;              // staging: row within 8-row issue
  const int lchk = (l & 7) ^ lrow8;      // staging: inverse-swizzled chunk
  const int m0 = blockIdx.y * 128, n0 = blockIdx.x * 64;

  f32x4 acc[4][2] = {};
  const int nk = K >> 6;   // K-tiles of 64 (K is 768 or 3072 -> nk even)

  STAGE(As0, Bs0, 0);
  __syncthreads();
  int kt = 0;
  for (; kt + 2 < nk; kt += 2) {
    STAGE(As1, Bs1, kt + 1);
    COMPUTE(As0, Bs0);
    __syncthreads();
    STAGE(As0, Bs0, kt + 2);
    COMPUTE(As1, Bs1);
    __syncthreads();
  }
  // kt == nk-2
  STAGE(As1, Bs1, kt + 1);
  COMPUTE(As0, Bs0);
  __syncthreads();
  COMPUTE(As1, Bs1);

#pragma unroll
  for (int i = 0; i < 4; ++i) {
#pragma unroll
    for (int j = 0; j < 2; ++j) {
#pragma unroll
      for (int rg = 0; rg < 4; ++rg) {
        const int m = m0 + wr * 64 + i * 16 + fk * 4 + rg;
        const int n = n0 + wc * 32 + j * 16 + fr;
        if (m < M) {
          float v = acc[i][j][rg] + bias[n];
          if (EPI == 1) v += resid[(size_t)m * N + n];
          if (EPI == 2) v = 0.5f * v * (1.f + erff(v * 0.70710678118654752f));
          if (EPI == 1) ((float*)Cv)[(size_t)m * N + n] = v;
          else ((__hip_bfloat16*)Cv)[(size_t)m * N + n] = __float2bfloat16(v);
        }
      }
    }
  }
}

// ---------------- CLS attention (bf16 qkv in, bf16 out) ----------------------
__global__ __launch_bounds__(256) void attn_cls(const __hip_bfloat16* __restrict__ qkv,
                                                __hip_bfloat16* __restrict__ out) {
  const int b = blockIdx.x / H_, h = blockIdx.x % H_;
  __shared__ float qs[64];
  __shared__ float sc[S_];
  __shared__ float red[4];
  __shared__ float part[4][64];
  const int t = threadIdx.x;
  const int wid = t >> 6, lane = t & 63;
  const int rowbase = b * S_;
  if (t < 64) qs[t] = __bfloat162float(qkv[(size_t)rowbase * 2304 + h * 64 + t]);
  __syncthreads();

  float lmax = -1e30f;
  for (int k = t; k < S_; k += 256) {
    const short8* kp8 = (const short8*)(qkv + (size_t)(rowbase + k) * 2304 + 768 + h * 64);
    float d = 0.f;
#pragma unroll
    for (int i = 0; i < 8; ++i) {
      const short8 v = kp8[i];
#pragma unroll
      for (int j = 0; j < 8; ++j) d += qs[i * 8 + j] * bf2f(v[j]);
    }
    d *= 0.125f;
    sc[k] = d;
    lmax = fmaxf(lmax, d);
  }
#pragma unroll
  for (int off = 32; off > 0; off >>= 1) lmax = fmaxf(lmax, __shfl_xor(lmax, off));
  if (lane == 0) red[wid] = lmax;
  __syncthreads();
  const float mx = fmaxf(fmaxf(red[0], red[1]), fmaxf(red[2], red[3]));
  __syncthreads();

  float lsum = 0.f;
  for (int k = t; k < S_; k += 256) {
    const float e = expf(sc[k] - mx);
    sc[k] = e;
    lsum += e;
  }
  lsum = wave_reduce_sum(lsum);
  if (lane == 0) red[wid] = lsum;
  __syncthreads();
  const float den = red[0] + red[1] + red[2] + red[3];

  float acc = 0.f;
  for (int k = wid; k < S_; k += 4) {
    acc += sc[k] * __bfloat162float(qkv[(size_t)(rowbase + k) * 2304 + 1536 + h * 64 + lane]);
  }
  part[wid][lane] = acc;
  __syncthreads();
  if (t < 64) {
    const float o = (part[0][t] + part[1][t] + part[2][t] + part[3][t]) / den;
    out[(size_t)rowbase * 768 + h * 64 + t] = __float2bfloat16(o);
  }
}

// ---------------- Patch attention: one wave per (b,h,p), 16 routed keys ------
__global__ __launch_bounds__(256) void attn_patch(const __hip_bfloat16* __restrict__ qkv,
                                                  const int* __restrict__ routes,
                                                  __hip_bfloat16* __restrict__ out) {
  const int gwid = (int)((blockIdx.x * 256 + threadIdx.x) >> 6);
  const int lane = threadIdx.x & 63;
  const int p = gwid & (P_ - 1);
  const int bh = gwid >> 10;
  const int h = bh % H_, b = bh / H_;
  const int qrow = b * S_ + p + 1;
  const float q = __bfloat162float(qkv[(size_t)qrow * 2304 + h * 64 + lane]);

  int krow[KN_];
#pragma unroll
  for (int j = 0; j < KN_; ++j) krow[j] = b * S_ + routes[p * KN_ + j] + 1;

  float sc[KN_];
#pragma unroll
  for (int j = 0; j < KN_; ++j) {
    float d = q * __bfloat162float(qkv[(size_t)krow[j] * 2304 + 768 + h * 64 + lane]);
    d = wave_reduce_sum(d);
    sc[j] = d * 0.125f;
  }
  float mx = sc[0];
#pragma unroll
  for (int j = 1; j < KN_; ++j) mx = fmaxf(mx, sc[j]);
  float den = 0.f;
#pragma unroll
  for (int j = 0; j < KN_; ++j) { sc[j] = expf(sc[j] - mx); den += sc[j]; }
  const float inv = 1.f / den;
  float o = 0.f;
#pragma unroll
  for (int j = 0; j < KN_; ++j)
    o += sc[j] * __bfloat162float(qkv[(size_t)krow[j] * 2304 + 1536 + h * 64 + lane]);
  out[(size_t)qrow * 768 + h * 64 + lane] = __float2bfloat16(o * inv);
}

// ---------------- launcher ---------------------------------------------------
extern "C" void kernel_launch(void* const* d_in, const int* in_sizes, int n_in,
                              void* d_out, int out_size, void* d_ws, size_t ws_size,
                              hipStream_t stream) {
  const float* x      = (const float*)d_in[0];
  const int*   routes = (const int*)d_in[1];
  const float* qkv_w  = (const float*)d_in[2];
  const float* qkv_b  = (const float*)d_in[3];
  const float* proj_w = (const float*)d_in[4];
  const float* proj_b = (const float*)d_in[5];
  const float* ln1_g  = (const float*)d_in[6];
  const float* ln1_b  = (const float*)d_in[7];
  const float* ln2_g  = (const float*)d_in[8];
  const float* ln2_b  = (const float*)d_in[9];
  const float* mlp_w1 = (const float*)d_in[10];
  const float* mlp_b1 = (const float*)d_in[11];
  const float* mlp_w2 = (const float*)d_in[12];
  const float* mlp_b2 = (const float*)d_in[13];
  float* outp = (float*)d_out;

  // ws layout (bf16 unless noted). A-tile overreads on the last M-tile land
  // in the subsequent buffer (finite values, rows masked at C-write).
  __hip_bfloat16* xn    = (__hip_bfloat16*)d_ws;            // NROWS*768
  __hip_bfloat16* qkv   = xn + (size_t)NROWS * 768;         // NROWS*2304
  __hip_bfloat16* attn  = qkv + (size_t)NROWS * 2304;       // NROWS*768
  float*          x1    = (float*)(attn + (size_t)NROWS * 768); // NROWS*768 f32
  __hip_bfloat16* h1    = (__hip_bfloat16*)(x1 + (size_t)NROWS * 768); // NROWS*3072
  __hip_bfloat16* wqkvT = h1 + (size_t)NROWS * 3072;        // 2304*768
  __hip_bfloat16* wprojT= wqkvT + (size_t)2304 * 768;       // 768*768
  __hip_bfloat16* w1T   = wprojT + (size_t)768 * 768;       // 3072*768
  __hip_bfloat16* w2T   = w1T + (size_t)3072 * 768;         // 768*3072

  const int mt = (NROWS + 127) / 128; // 33

  // weight transpose+convert (f32 [K][N] -> bf16 [N][K])
  wtrans<<<dim3(2304 / 32, 768 / 32), 256, 0, stream>>>(qkv_w, wqkvT, 768, 2304);
  wtrans<<<dim3(768 / 32, 768 / 32), 256, 0, stream>>>(proj_w, wprojT, 768, 768);
  wtrans<<<dim3(3072 / 32, 768 / 32), 256, 0, stream>>>(mlp_w1, w1T, 768, 3072);
  wtrans<<<dim3(768 / 32, 3072 / 32), 256, 0, stream>>>(mlp_w2, w2T, 3072, 768);

  ln_bf16<<<NROWS, 256, 0, stream>>>(x, ln1_g, ln1_b, xn);
  gemm_mfma<0><<<dim3(2304 / 64, mt), 256, 0, stream>>>(
      xn, wqkvT, qkv_b, nullptr, qkv, NROWS, 2304, 768);
  attn_cls<<<B_ * H_, 256, 0, stream>>>(qkv, attn);
  attn_patch<<<B_ * H_ * P_ / 4, 256, 0, stream>>>(qkv, routes, attn);
  gemm_mfma<1><<<dim3(768 / 64, mt), 256, 0, stream>>>(
      attn, wprojT, proj_b, x, x1, NROWS, 768, 768);
  ln_bf16<<<NROWS, 256, 0, stream>>>(x1, ln2_g, ln2_b, xn);
  gemm_mfma<2><<<dim3(3072 / 64, mt), 256, 0, stream>>>(
      xn, w1T, mlp_b1, nullptr, h1, NROWS, 3072, 768);
  gemm_mfma<1><<<dim3(768 / 64, mt), 256, 0, stream>>>(
      h1, w2T, mlp_b2, x1, outp, NROWS, 768, 3072);
}

// Round 8
// 333.279 us; speedup vs baseline: 1.3860x; 1.1971x over previous
//
#include <hip/hip_runtime.h>
#include <hip/hip_bf16.h>
#include <cmath>

#define B_ 4
#define P_ 1024
#define KN_ 16
#define D_ 768
#define H_ 12
#define S_ 1025
#define NROWS (B_ * S_) // 4100
#define NC_ 32          // CLS key chunks
#define CH_ 33          // keys per chunk (32*33 = 1056 >= 1025; last chunk = 2)

typedef __attribute__((ext_vector_type(8))) short short8;
typedef __attribute__((ext_vector_type(4))) float f32x4;

__device__ __forceinline__ float bf2f(short u) {
  return __uint_as_float(((unsigned int)(unsigned short)u) << 16);
}

__device__ __forceinline__ float wave_reduce_sum(float v) {
#pragma unroll
  for (int off = 32; off > 0; off >>= 1) v += __shfl_xor(v, off);
  return v;
}

__device__ __forceinline__ void gload16(const void* g, void* l) {
  __builtin_amdgcn_global_load_lds(
      (const __attribute__((address_space(1))) unsigned int*)g,
      (__attribute__((address_space(3))) unsigned int*)l, 16, 0, 0);
}

// ---------------- LayerNorm over D=768 -> bf16 out ---------------------------
__global__ __launch_bounds__(256) void ln_bf16(const float* __restrict__ x,
                                               const float* __restrict__ g,
                                               const float* __restrict__ b,
                                               __hip_bfloat16* __restrict__ y) {
  const int row = blockIdx.x;
  const float* xr = x + (size_t)row * D_;
  __hip_bfloat16* yr = y + (size_t)row * D_;
  const int t = threadIdx.x;
  const float v0 = xr[t], v1 = xr[t + 256], v2 = xr[t + 512];
  float s = v0 + v1 + v2;
  float ss = v0 * v0 + v1 * v1 + v2 * v2;
  s = wave_reduce_sum(s);
  ss = wave_reduce_sum(ss);
  __shared__ float rs[4], rss[4];
  const int wid = t >> 6, lane = t & 63;
  if (lane == 0) { rs[wid] = s; rss[wid] = ss; }
  __syncthreads();
  const float tot = rs[0] + rs[1] + rs[2] + rs[3];
  const float tot2 = rss[0] + rss[1] + rss[2] + rss[3];
  const float mean = tot * (1.0f / D_);
  const float var = tot2 * (1.0f / D_) - mean * mean;
  const float rstd = rsqrtf(var + 1e-5f);
  yr[t]       = __float2bfloat16((v0 - mean) * rstd * g[t]       + b[t]);
  yr[t + 256] = __float2bfloat16((v1 - mean) * rstd * g[t + 256] + b[t + 256]);
  yr[t + 512] = __float2bfloat16((v2 - mean) * rstd * g[t + 512] + b[t + 512]);
}

// ---------------- weight transpose+convert: W[K][N] f32 -> WT[N][K] bf16 -----
__global__ __launch_bounds__(256) void wtrans(const float* __restrict__ W,
                                              __hip_bfloat16* __restrict__ WT,
                                              int K, int N) {
  __shared__ float t[32][33];
  const int tx = threadIdx.x & 31, ty = threadIdx.x >> 5; // 32 x 8
  const int n0 = blockIdx.x * 32, k0 = blockIdx.y * 32;
#pragma unroll
  for (int i = 0; i < 32; i += 8)
    t[ty + i][tx] = W[(size_t)(k0 + ty + i) * N + n0 + tx];
  __syncthreads();
#pragma unroll
  for (int i = 0; i < 32; i += 8)
    WT[(size_t)(n0 + ty + i) * K + k0 + tx] = __float2bfloat16(t[tx][ty + i]);
}

// ---------------- bf16 MFMA GEMM: C[MxN] = A[MxK] @ WT[NxK]^T + bias (+epi) --
// BM=128, BN=64, BK=64. 4 waves, each 64x32 (4x2 frags of 16x16x32).
// Double-buffered static As0/As1; 2-phase pipeline (stage t+1 while
// computing t). Rule-21 swizzle: LDS[row][c] = G[row][c ^ (row&7)].
#define STAGE(AS, BS, kt)                                                      \
  {                                                                            \
    _Pragma("unroll")                                                          \
    for (int q = 0; q < 4; ++q)                                                \
      gload16(A + (size_t)(m0 + w * 32 + q * 8 + lrow8) * K + (kt) * 64 +      \
                  lchk * 8,                                                    \
              &AS[w * 32 + q * 8][0]);                                         \
    _Pragma("unroll")                                                          \
    for (int q = 0; q < 2; ++q)                                                \
      gload16(WT + (size_t)(n0 + w * 16 + q * 8 + lrow8) * K + (kt) * 64 +     \
                  lchk * 8,                                                    \
              &BS[w * 16 + q * 8][0]);                                         \
  }

#define COMPUTE(AS, BS)                                                        \
  {                                                                            \
    short8 af[4][2], bfr[2][2];                                                \
    _Pragma("unroll")                                                          \
    for (int i = 0; i < 4; ++i) {                                              \
      _Pragma("unroll")                                                        \
      for (int s = 0; s < 2; ++s) {                                            \
        const int ra = wr * 64 + i * 16 + fr;                                  \
        af[i][s] = *(const short8*)&AS[ra][((s * 4 + fk) ^ (ra & 7)) * 8];     \
      }                                                                        \
    }                                                                          \
    _Pragma("unroll")                                                          \
    for (int j = 0; j < 2; ++j) {                                              \
      _Pragma("unroll")                                                        \
      for (int s = 0; s < 2; ++s) {                                            \
        const int rb = wc * 32 + j * 16 + fr;                                  \
        bfr[j][s] = *(const short8*)&BS[rb][((s * 4 + fk) ^ (rb & 7)) * 8];    \
      }                                                                        \
    }                                                                          \
    _Pragma("unroll")                                                          \
    for (int i = 0; i < 4; ++i) {                                              \
      _Pragma("unroll")                                                        \
      for (int j = 0; j < 2; ++j) {                                            \
        _Pragma("unroll")                                                      \
        for (int s = 0; s < 2; ++s)                                            \
          acc[i][j] = __builtin_amdgcn_mfma_f32_16x16x32_bf16(                 \
              af[i][s], bfr[j][s], acc[i][j], 0, 0, 0);                        \
      }                                                                        \
    }                                                                          \
  }

template <int EPI>
__global__ __launch_bounds__(256) void gemm_mfma(
    const __hip_bfloat16* __restrict__ A, const __hip_bfloat16* __restrict__ WT,
    const float* __restrict__ bias, const float* __restrict__ resid,
    void* __restrict__ Cv, int M, int N, int K) {
  __shared__ __align__(16) __hip_bfloat16 As0[128][64], As1[128][64];
  __shared__ __align__(16) __hip_bfloat16 Bs0[64][64], Bs1[64][64];
  const int tid = threadIdx.x;
  const int l = tid & 63, w = tid >> 6;
  const int wr = w >> 1, wc = w & 1;     // wave-row (64), wave-col (32)
  const int fr = l & 15, fk = l >> 4;    // frag row / k-subchunk
  const int lrow8 = l >> 3;              // staging: row within 8-row issue
  const int lchk = (l & 7) ^ lrow8;      // staging: inverse-swizzled chunk
  const int m0 = blockIdx.y * 128, n0 = blockIdx.x * 64;

  f32x4 acc[4][2] = {};
  const int nk = K >> 6;   // K-tiles of 64 (K is 768 or 3072 -> nk even)

  STAGE(As0, Bs0, 0);
  __syncthreads();
  int kt = 0;
  for (; kt + 2 < nk; kt += 2) {
    STAGE(As1, Bs1, kt + 1);
    COMPUTE(As0, Bs0);
    __syncthreads();
    STAGE(As0, Bs0, kt + 2);
    COMPUTE(As1, Bs1);
    __syncthreads();
  }
  // kt == nk-2
  STAGE(As1, Bs1, kt + 1);
  COMPUTE(As0, Bs0);
  __syncthreads();
  COMPUTE(As1, Bs1);

#pragma unroll
  for (int i = 0; i < 4; ++i) {
#pragma unroll
    for (int j = 0; j < 2; ++j) {
#pragma unroll
      for (int rg = 0; rg < 4; ++rg) {
        const int m = m0 + wr * 64 + i * 16 + fk * 4 + rg;
        const int n = n0 + wc * 32 + j * 16 + fr;
        if (m < M) {
          float v = acc[i][j][rg] + bias[n];
          if (EPI == 1) v += resid[(size_t)m * N + n];
          if (EPI == 2) v = 0.5f * v * (1.f + erff(v * 0.70710678118654752f));
          if (EPI == 1) ((float*)Cv)[(size_t)m * N + n] = v;
          else ((__hip_bfloat16*)Cv)[(size_t)m * N + n] = __float2bfloat16(v);
        }
      }
    }
  }
}

// ---------------- CLS attention, flash-decode split --------------------------
// Part: grid (B*H*NC_), each block owns <=CH_ keys of one (b,h); emits
// chunk-local (m, l, partial unnormalized V-sum[64]) to ws.
__global__ __launch_bounds__(256) void attn_cls_part(
    const __hip_bfloat16* __restrict__ qkv, float* __restrict__ part) {
  const int bh = blockIdx.x / NC_, chunk = blockIdx.x % NC_;
  const int b = bh / H_, h = bh % H_;
  const int c0 = chunk * CH_;
  const int nk = min(CH_, S_ - c0);       // >= 2 for all 32 chunks
  __shared__ float qs[64];
  __shared__ float sc[CH_];
  __shared__ float redm, redl;
  __shared__ float pl[4][64];
  const int t = threadIdx.x;
  const int wid = t >> 6, lane = t & 63;
  const int rowbase = b * S_;
  if (t < 64) qs[t] = __bfloat162float(qkv[(size_t)rowbase * 2304 + h * 64 + t]);
  __syncthreads();

  if (t < nk) {  // one thread per key (all in wave 0: nk <= 33)
    const short8* kp8 =
        (const short8*)(qkv + (size_t)(rowbase + c0 + t) * 2304 + 768 + h * 64);
    float d = 0.f;
#pragma unroll
    for (int i = 0; i < 8; ++i) {
      const short8 v = kp8[i];
#pragma unroll
      for (int j = 0; j < 8; ++j) d += qs[i * 8 + j] * bf2f(v[j]);
    }
    sc[t] = d * 0.125f;
  }
  __syncthreads();
  if (wid == 0) {  // chunk max + exp + sum (nk <= 64: single wave pass)
    float v = (lane < nk) ? sc[lane] : -1e30f;
    float m = v;
#pragma unroll
    for (int off = 32; off > 0; off >>= 1) m = fmaxf(m, __shfl_xor(m, off));
    float e = (lane < nk) ? expf(v - m) : 0.f;
    if (lane < nk) sc[lane] = e;
    const float lsum = wave_reduce_sum(e);
    if (lane == 0) { redm = m; redl = lsum; }
  }
  __syncthreads();

  float acc = 0.f;  // V phase: lane = d, waves stride keys
  for (int k = wid; k < nk; k += 4)
    acc += sc[k] *
           __bfloat162float(qkv[(size_t)(rowbase + c0 + k) * 2304 + 1536 + h * 64 + lane]);
  pl[wid][lane] = acc;
  __syncthreads();
  float* po = part + (size_t)(bh * NC_ + chunk) * 68;
  if (t < 64) po[2 + t] = pl[0][t] + pl[1][t] + pl[2][t] + pl[3][t];
  else if (t == 64) po[0] = redm;
  else if (t == 65) po[1] = redl;
}

// Merge: grid (B*H_), one wave; log-sum-exp combine of NC_ partials.
__global__ __launch_bounds__(64) void attn_cls_merge(
    const float* __restrict__ part, __hip_bfloat16* __restrict__ out) {
  const int bh = blockIdx.x;
  const int b = bh / H_, h = bh % H_;
  const int lane = threadIdx.x;
  const float* pb = part + (size_t)bh * NC_ * 68;
  float M = -1e30f;
#pragma unroll
  for (int i = 0; i < NC_; ++i) M = fmaxf(M, pb[i * 68]);
  float den = 0.f, o = 0.f;
#pragma unroll
  for (int i = 0; i < NC_; ++i) {
    const float wgt = expf(pb[i * 68] - M);
    den += wgt * pb[i * 68 + 1];
    o += wgt * pb[i * 68 + 2 + lane];
  }
  out[(size_t)(b * S_) * 768 + h * 64 + lane] = __float2bfloat16(o / den);
}

// ---------------- Patch attention: one wave per (b,h,p), 16 routed keys ------
__global__ __launch_bounds__(256) void attn_patch(const __hip_bfloat16* __restrict__ qkv,
                                                  const int* __restrict__ routes,
                                                  __hip_bfloat16* __restrict__ out) {
  const int gwid = (int)((blockIdx.x * 256 + threadIdx.x) >> 6);
  const int lane = threadIdx.x & 63;
  const int p = gwid & (P_ - 1);
  const int bh = gwid >> 10;
  const int h = bh % H_, b = bh / H_;
  const int qrow = b * S_ + p + 1;
  const float q = __bfloat162float(qkv[(size_t)qrow * 2304 + h * 64 + lane]);

  int krow[KN_];
#pragma unroll
  for (int j = 0; j < KN_; ++j) krow[j] = b * S_ + routes[p * KN_ + j] + 1;

  float sc[KN_];
#pragma unroll
  for (int j = 0; j < KN_; ++j) {
    float d = q * __bfloat162float(qkv[(size_t)krow[j] * 2304 + 768 + h * 64 + lane]);
    d = wave_reduce_sum(d);
    sc[j] = d * 0.125f;
  }
  float mx = sc[0];
#pragma unroll
  for (int j = 1; j < KN_; ++j) mx = fmaxf(mx, sc[j]);
  float den = 0.f;
#pragma unroll
  for (int j = 0; j < KN_; ++j) { sc[j] = expf(sc[j] - mx); den += sc[j]; }
  const float inv = 1.f / den;
  float o = 0.f;
#pragma unroll
  for (int j = 0; j < KN_; ++j)
    o += sc[j] * __bfloat162float(qkv[(size_t)krow[j] * 2304 + 1536 + h * 64 + lane]);
  out[(size_t)qrow * 768 + h * 64 + lane] = __float2bfloat16(o * inv);
}

// ---------------- launcher ---------------------------------------------------
extern "C" void kernel_launch(void* const* d_in, const int* in_sizes, int n_in,
                              void* d_out, int out_size, void* d_ws, size_t ws_size,
                              hipStream_t stream) {
  const float* x      = (const float*)d_in[0];
  const int*   routes = (const int*)d_in[1];
  const float* qkv_w  = (const float*)d_in[2];
  const float* qkv_b  = (const float*)d_in[3];
  const float* proj_w = (const float*)d_in[4];
  const float* proj_b = (const float*)d_in[5];
  const float* ln1_g  = (const float*)d_in[6];
  const float* ln1_b  = (const float*)d_in[7];
  const float* ln2_g  = (const float*)d_in[8];
  const float* ln2_b  = (const float*)d_in[9];
  const float* mlp_w1 = (const float*)d_in[10];
  const float* mlp_b1 = (const float*)d_in[11];
  const float* mlp_w2 = (const float*)d_in[12];
  const float* mlp_b2 = (const float*)d_in[13];
  float* outp = (float*)d_out;

  // ws layout (bf16 unless noted). A-tile overreads on the last M-tile land
  // in the subsequent buffer (finite values, rows masked at C-write).
  __hip_bfloat16* xn    = (__hip_bfloat16*)d_ws;            // NROWS*768
  __hip_bfloat16* qkv   = xn + (size_t)NROWS * 768;         // NROWS*2304
  __hip_bfloat16* attn  = qkv + (size_t)NROWS * 2304;       // NROWS*768
  float*          x1    = (float*)(attn + (size_t)NROWS * 768); // NROWS*768 f32
  __hip_bfloat16* h1    = (__hip_bfloat16*)(x1 + (size_t)NROWS * 768); // NROWS*3072
  __hip_bfloat16* wqkvT = h1 + (size_t)NROWS * 3072;        // 2304*768
  __hip_bfloat16* wprojT= wqkvT + (size_t)2304 * 768;       // 768*768
  __hip_bfloat16* w1T   = wprojT + (size_t)768 * 768;       // 3072*768
  __hip_bfloat16* w2T   = w1T + (size_t)3072 * 768;         // 768*3072
  float*          clsp  = (float*)(w2T + (size_t)768 * 3072); // 48*NC_*68 f32

  const int mt = (NROWS + 127) / 128; // 33

  // weight transpose+convert (f32 [K][N] -> bf16 [N][K])
  wtrans<<<dim3(2304 / 32, 768 / 32), 256, 0, stream>>>(qkv_w, wqkvT, 768, 2304);
  wtrans<<<dim3(768 / 32, 768 / 32), 256, 0, stream>>>(proj_w, wprojT, 768, 768);
  wtrans<<<dim3(3072 / 32, 768 / 32), 256, 0, stream>>>(mlp_w1, w1T, 768, 3072);
  wtrans<<<dim3(768 / 32, 3072 / 32), 256, 0, stream>>>(mlp_w2, w2T, 3072, 768);

  ln_bf16<<<NROWS, 256, 0, stream>>>(x, ln1_g, ln1_b, xn);
  gemm_mfma<0><<<dim3(2304 / 64, mt), 256, 0, stream>>>(
      xn, wqkvT, qkv_b, nullptr, qkv, NROWS, 2304, 768);
  attn_cls_part<<<B_ * H_ * NC_, 256, 0, stream>>>(qkv, clsp);
  attn_cls_merge<<<B_ * H_, 64, 0, stream>>>(clsp, attn);
  attn_patch<<<B_ * H_ * P_ / 4, 256, 0, stream>>>(qkv, routes, attn);
  gemm_mfma<1><<<dim3(768 / 64, mt), 256, 0, stream>>>(
      attn, wprojT, proj_b, x, x1, NROWS, 768, 768);
  ln_bf16<<<NROWS, 256, 0, stream>>>(x1, ln2_g, ln2_b, xn);
  gemm_mfma<2><<<dim3(3072 / 64, mt), 256, 0, stream>>>(
      xn, w1T, mlp_b1, nullptr, h1, NROWS, 3072, 768);
  gemm_mfma<1><<<dim3(768 / 64, mt), 256, 0, stream>>>(
      h1, w2T, mlp_b2, x1, outp, NROWS, 768, 3072);
}

// Round 11
// 301.917 us; speedup vs baseline: 1.5300x; 1.1039x over previous
//
#include <hip/hip_runtime.h>
#include <hip/hip_bf16.h>
#include <cmath>

#define B_ 4
#define P_ 1024
#define KN_ 16
#define D_ 768
#define H_ 12
#define S_ 1025
#define NROWS (B_ * S_) // 4100
#define NC_ 32          // CLS key chunks
#define CH_ 33          // keys per chunk (32*33 = 1056 >= 1025; last chunk = 2)

typedef __attribute__((ext_vector_type(8))) short short8;
typedef __attribute__((ext_vector_type(4))) float f32x4;

__device__ __forceinline__ float bf2f(short u) {
  return __uint_as_float(((unsigned int)(unsigned short)u) << 16);
}

__device__ __forceinline__ float wave_reduce_sum(float v) {
#pragma unroll
  for (int off = 32; off > 0; off >>= 1) v += __shfl_xor(v, off);
  return v;
}

__device__ __forceinline__ void gload16(const void* g, void* l) {
  __builtin_amdgcn_global_load_lds(
      (const __attribute__((address_space(1))) unsigned int*)g,
      (__attribute__((address_space(3))) unsigned int*)l, 16, 0, 0);
}

// ---------------- LayerNorm over D=768 -> bf16 out ---------------------------
__global__ __launch_bounds__(256) void ln_bf16(const float* __restrict__ x,
                                               const float* __restrict__ g,
                                               const float* __restrict__ b,
                                               __hip_bfloat16* __restrict__ y) {
  const int row = blockIdx.x;
  const float* xr = x + (size_t)row * D_;
  __hip_bfloat16* yr = y + (size_t)row * D_;
  const int t = threadIdx.x;
  const float v0 = xr[t], v1 = xr[t + 256], v2 = xr[t + 512];
  float s = v0 + v1 + v2;
  float ss = v0 * v0 + v1 * v1 + v2 * v2;
  s = wave_reduce_sum(s);
  ss = wave_reduce_sum(ss);
  __shared__ float rs[4], rss[4];
  const int wid = t >> 6, lane = t & 63;
  if (lane == 0) { rs[wid] = s; rss[wid] = ss; }
  __syncthreads();
  const float tot = rs[0] + rs[1] + rs[2] + rs[3];
  const float tot2 = rss[0] + rss[1] + rss[2] + rss[3];
  const float mean = tot * (1.0f / D_);
  const float var = tot2 * (1.0f / D_) - mean * mean;
  const float rstd = rsqrtf(var + 1e-5f);
  yr[t]       = __float2bfloat16((v0 - mean) * rstd * g[t]       + b[t]);
  yr[t + 256] = __float2bfloat16((v1 - mean) * rstd * g[t + 256] + b[t + 256]);
  yr[t + 512] = __float2bfloat16((v2 - mean) * rstd * g[t + 512] + b[t + 512]);
}

// ---------------- weight transpose+convert: W[K][N] f32 -> WT[N][K] bf16 -----
__global__ __launch_bounds__(256) void wtrans(const float* __restrict__ W,
                                              __hip_bfloat16* __restrict__ WT,
                                              int K, int N) {
  __shared__ float t[32][33];
  const int tx = threadIdx.x & 31, ty = threadIdx.x >> 5; // 32 x 8
  const int n0 = blockIdx.x * 32, k0 = blockIdx.y * 32;
#pragma unroll
  for (int i = 0; i < 32; i += 8)
    t[ty + i][tx] = W[(size_t)(k0 + ty + i) * N + n0 + tx];
  __syncthreads();
#pragma unroll
  for (int i = 0; i < 32; i += 8)
    WT[(size_t)(n0 + ty + i) * K + k0 + tx] = __float2bfloat16(t[tx][ty + i]);
}

// ---------------- bf16 MFMA GEMM: C[MxN] = A[MxK] @ WT[NxK]^T + bias (+epi) --
// BM=128, BN=64, BK=64. 4 waves, each 64x32 (4x2 frags of 16x16x32).
// Double-buffered static As0/As1; 2-phase pipeline (stage t+1 while
// computing t). Rule-21 swizzle: LDS[row][c] = G[row][c ^ (row&7)].
#define STAGE(AS, BS, kt)                                                      \
  {                                                                            \
    _Pragma("unroll")                                                          \
    for (int q = 0; q < 4; ++q)                                                \
      gload16(A + (size_t)(m0 + w * 32 + q * 8 + lrow8) * K + (kt) * 64 +      \
                  lchk * 8,                                                    \
              &AS[w * 32 + q * 8][0]);                                         \
    _Pragma("unroll")                                                          \
    for (int q = 0; q < 2; ++q)                                                \
      gload16(WT + (size_t)(n0 + w * 16 + q * 8 + lrow8) * K + (kt) * 64 +     \
                  lchk * 8,                                                    \
              &BS[w * 16 + q * 8][0]);                                         \
  }

#define COMPUTE(AS, BS)                                                        \
  {                                                                            \
    short8 af[4][2], bfr[2][2];                                                \
    _Pragma("unroll")                                                          \
    for (int i = 0; i < 4; ++i) {                                              \
      _Pragma("unroll")                                                        \
      for (int s = 0; s < 2; ++s) {                                            \
        const int ra = wr * 64 + i * 16 + fr;                                  \
        af[i][s] = *(const short8*)&AS[ra][((s * 4 + fk) ^ (ra & 7)) * 8];     \
      }                                                                        \
    }                                                                          \
    _Pragma("unroll")                                                          \
    for (int j = 0; j < 2; ++j) {                                              \
      _Pragma("unroll")                                                        \
      for (int s = 0; s < 2; ++s) {                                            \
        const int rb = wc * 32 + j * 16 + fr;                                  \
        bfr[j][s] = *(const short8*)&BS[rb][((s * 4 + fk) ^ (rb & 7)) * 8];    \
      }                                                                        \
    }                                                                          \
    _Pragma("unroll")                                                          \
    for (int i = 0; i < 4; ++i) {                                              \
      _Pragma("unroll")                                                        \
      for (int j = 0; j < 2; ++j) {                                            \
        _Pragma("unroll")                                                      \
        for (int s = 0; s < 2; ++s)                                            \
          acc[i][j] = __builtin_amdgcn_mfma_f32_16x16x32_bf16(                 \
              af[i][s], bfr[j][s], acc[i][j], 0, 0, 0);                        \
      }                                                                        \
    }                                                                          \
  }

template <int EPI>
__global__ __launch_bounds__(256) void gemm_mfma(
    const __hip_bfloat16* __restrict__ A, const __hip_bfloat16* __restrict__ WT,
    const float* __restrict__ bias, const float* __restrict__ resid,
    void* __restrict__ Cv, int M, int N, int K) {
  __shared__ __align__(16) __hip_bfloat16 As0[128][64], As1[128][64];
  __shared__ __align__(16) __hip_bfloat16 Bs0[64][64], Bs1[64][64];
  const int tid = threadIdx.x;
  const int l = tid & 63, w = tid >> 6;
  const int wr = w >> 1, wc = w & 1;     // wave-row (64), wave-col (32)
  const int fr = l & 15, fk = l >> 4;    // frag row / k-subchunk
  const int lrow8 = l >> 3;              // staging: row within 8-row issue
  const int lchk = (l & 7) ^ lrow8;      // staging: inverse-swizzled chunk
  const int m0 = blockIdx.y * 128, n0 = blockIdx.x * 64;

  f32x4 acc[4][2] = {};
  const int nk = K >> 6;   // K-tiles of 64 (K is 768 or 3072 -> nk even)

  STAGE(As0, Bs0, 0);
  __syncthreads();
  int kt = 0;
  for (; kt + 2 < nk; kt += 2) {
    STAGE(As1, Bs1, kt + 1);
    COMPUTE(As0, Bs0);
    __syncthreads();
    STAGE(As0, Bs0, kt + 2);
    COMPUTE(As1, Bs1);
    __syncthreads();
  }
  // kt == nk-2
  STAGE(As1, Bs1, kt + 1);
  COMPUTE(As0, Bs0);
  __syncthreads();
  COMPUTE(As1, Bs1);

#pragma unroll
  for (int i = 0; i < 4; ++i) {
#pragma unroll
    for (int j = 0; j < 2; ++j) {
#pragma unroll
      for (int rg = 0; rg < 4; ++rg) {
        const int m = m0 + wr * 64 + i * 16 + fk * 4 + rg;
        const int n = n0 + wc * 32 + j * 16 + fr;
        if (m < M) {
          float v = acc[i][j][rg] + bias[n];
          if (EPI == 1) v += resid[(size_t)m * N + n];
          if (EPI == 2) v = 0.5f * v * (1.f + erff(v * 0.70710678118654752f));
          if (EPI == 1) ((float*)Cv)[(size_t)m * N + n] = v;
          else ((__hip_bfloat16*)Cv)[(size_t)m * N + n] = __float2bfloat16(v);
        }
      }
    }
  }
}

// ---------------- CLS attention, flash-decode split --------------------------
__global__ __launch_bounds__(256) void attn_cls_part(
    const __hip_bfloat16* __restrict__ qkv, float* __restrict__ part) {
  const int bh = blockIdx.x / NC_, chunk = blockIdx.x % NC_;
  const int b = bh / H_, h = bh % H_;
  const int c0 = chunk * CH_;
  const int nk = min(CH_, S_ - c0);       // >= 2 for all 32 chunks
  __shared__ float qs[64];
  __shared__ float sc[CH_];
  __shared__ float redm, redl;
  __shared__ float pl[4][64];
  const int t = threadIdx.x;
  const int wid = t >> 6, lane = t & 63;
  const int rowbase = b * S_;
  if (t < 64) qs[t] = __bfloat162float(qkv[(size_t)rowbase * 2304 + h * 64 + t]);
  __syncthreads();

  if (t < nk) {  // one thread per key (all in wave 0: nk <= 33)
    const short8* kp8 =
        (const short8*)(qkv + (size_t)(rowbase + c0 + t) * 2304 + 768 + h * 64);
    float d = 0.f;
#pragma unroll
    for (int i = 0; i < 8; ++i) {
      const short8 v = kp8[i];
#pragma unroll
      for (int j = 0; j < 8; ++j) d += qs[i * 8 + j] * bf2f(v[j]);
    }
    sc[t] = d * 0.125f;
  }
  __syncthreads();
  if (wid == 0) {  // chunk max + exp + sum (nk <= 64: single wave pass)
    float v = (lane < nk) ? sc[lane] : -1e30f;
    float m = v;
#pragma unroll
    for (int off = 32; off > 0; off >>= 1) m = fmaxf(m, __shfl_xor(m, off));
    float e = (lane < nk) ? expf(v - m) : 0.f;
    if (lane < nk) sc[lane] = e;
    const float lsum = wave_reduce_sum(e);
    if (lane == 0) { redm = m; redl = lsum; }
  }
  __syncthreads();

  float acc = 0.f;  // V phase: lane = d, waves stride keys
  for (int k = wid; k < nk; k += 4)
    acc += sc[k] *
           __bfloat162float(qkv[(size_t)(rowbase + c0 + k) * 2304 + 1536 + h * 64 + lane]);
  pl[wid][lane] = acc;
  __syncthreads();
  float* po = part + (size_t)(bh * NC_ + chunk) * 68;
  if (t < 64) po[2 + t] = pl[0][t] + pl[1][t] + pl[2][t] + pl[3][t];
  else if (t == 64) po[0] = redm;
  else if (t == 65) po[1] = redl;
}

// Merge: grid (B*H_), one wave; log-sum-exp combine of NC_ partials.
__global__ __launch_bounds__(64) void attn_cls_merge(
    const float* __restrict__ part, __hip_bfloat16* __restrict__ out) {
  const int bh = blockIdx.x;
  const int b = bh / H_, h = bh % H_;
  const int lane = threadIdx.x;
  const float* pb = part + (size_t)bh * NC_ * 68;
  float M = -1e30f;
#pragma unroll
  for (int i = 0; i < NC_; ++i) M = fmaxf(M, pb[i * 68]);
  float den = 0.f, o = 0.f;
#pragma unroll
  for (int i = 0; i < NC_; ++i) {
    const float wgt = expf(pb[i * 68] - M);
    den += wgt * pb[i * 68 + 1];
    o += wgt * pb[i * 68 + 2 + lane];
  }
  out[(size_t)(b * S_) * 768 + h * 64 + lane] = __float2bfloat16(o / den);
}

// ---------------- Patch attention v2: 4-lanes-per-key layout -----------------
// One wave per (b,h,p). Lane = j*4+s: key j (0..15), dim-quarter s (0..3).
// QK: 16-dim partial dot per lane (2x short8 loads), reduce over s = 2 shfl.
// Softmax: max/sum butterflies over lane bits 2..5 (j bits); 1 expf/lane.
// V: lane = dim d; e_j / krow_j broadcast via __shfl; 16 coalesced bf16 loads.
__global__ __launch_bounds__(256) void attn_patch(const __hip_bfloat16* __restrict__ qkv,
                                                  const int* __restrict__ routes,
                                                  __hip_bfloat16* __restrict__ out) {
  const int gwid = (int)((blockIdx.x * 256 + threadIdx.x) >> 6);
  const int lane = threadIdx.x & 63;
  const int p = gwid & (P_ - 1);
  const int bh = gwid >> 10;
  const int h = bh % H_, b = bh / H_;
  const int qrow = b * S_ + p + 1;
  const int j = lane >> 2, s = lane & 3;

  // Q quarter -> f32 regs (lanes sharing s hit the same addresses; L1 broadcast)
  const short8* qp = (const short8*)(qkv + (size_t)qrow * 2304 + h * 64 + s * 16);
  const short8 q0 = qp[0], q1 = qp[1];
  float qf[16];
#pragma unroll
  for (int i = 0; i < 8; ++i) { qf[i] = bf2f(q0[i]); qf[8 + i] = bf2f(q1[i]); }

  const int krow = b * S_ + routes[p * KN_ + j] + 1;

  // QK partial dot over this lane's 16 dims
  const short8* kp = (const short8*)(qkv + (size_t)krow * 2304 + 768 + h * 64 + s * 16);
  const short8 k0 = kp[0], k1 = kp[1];
  float d = 0.f;
#pragma unroll
  for (int i = 0; i < 8; ++i) { d += qf[i] * bf2f(k0[i]); d += qf[8 + i] * bf2f(k1[i]); }
  d += __shfl_xor(d, 1);
  d += __shfl_xor(d, 2);          // full dot, replicated across the 4 s-lanes
  d *= 0.125f;

  // softmax over the 16 keys (butterfly over j bits = lane bits 2..5)
  float mx = d;
#pragma unroll
  for (int off = 4; off <= 32; off <<= 1) mx = fmaxf(mx, __shfl_xor(mx, off));
  const float e = expf(d - mx);
  float den = e;
#pragma unroll
  for (int off = 4; off <= 32; off <<= 1) den += __shfl_xor(den, off);
  const float inv = 1.f / den;

  // V: lane = output dim; broadcast (e, krow) from lane jj*4
  float o = 0.f;
#pragma unroll
  for (int jj = 0; jj < KN_; ++jj) {
    const float ej = __shfl(e, jj * 4);
    const int krj = __shfl(krow, jj * 4);
    o += ej * __bfloat162float(qkv[(size_t)krj * 2304 + 1536 + h * 64 + lane]);
  }
  out[(size_t)qrow * 768 + h * 64 + lane] = __float2bfloat16(o * inv);
}

// ---------------- launcher ---------------------------------------------------
extern "C" void kernel_launch(void* const* d_in, const int* in_sizes, int n_in,
                              void* d_out, int out_size, void* d_ws, size_t ws_size,
                              hipStream_t stream) {
  const float* x      = (const float*)d_in[0];
  const int*   routes = (const int*)d_in[1];
  const float* qkv_w  = (const float*)d_in[2];
  const float* qkv_b  = (const float*)d_in[3];
  const float* proj_w = (const float*)d_in[4];
  const float* proj_b = (const float*)d_in[5];
  const float* ln1_g  = (const float*)d_in[6];
  const float* ln1_b  = (const float*)d_in[7];
  const float* ln2_g  = (const float*)d_in[8];
  const float* ln2_b  = (const float*)d_in[9];
  const float* mlp_w1 = (const float*)d_in[10];
  const float* mlp_b1 = (const float*)d_in[11];
  const float* mlp_w2 = (const float*)d_in[12];
  const float* mlp_b2 = (const float*)d_in[13];
  float* outp = (float*)d_out;

  // ws layout (bf16 unless noted). A-tile overreads on the last M-tile land
  // in the subsequent buffer (finite values, rows masked at C-write).
  __hip_bfloat16* xn    = (__hip_bfloat16*)d_ws;            // NROWS*768
  __hip_bfloat16* qkv   = xn + (size_t)NROWS * 768;         // NROWS*2304
  __hip_bfloat16* attn  = qkv + (size_t)NROWS * 2304;       // NROWS*768
  float*          x1    = (float*)(attn + (size_t)NROWS * 768); // NROWS*768 f32
  __hip_bfloat16* h1    = (__hip_bfloat16*)(x1 + (size_t)NROWS * 768); // NROWS*3072
  __hip_bfloat16* wqkvT = h1 + (size_t)NROWS * 3072;        // 2304*768
  __hip_bfloat16* wprojT= wqkvT + (size_t)2304 * 768;       // 768*768
  __hip_bfloat16* w1T   = wprojT + (size_t)768 * 768;       // 3072*768
  __hip_bfloat16* w2T   = w1T + (size_t)3072 * 768;         // 768*3072
  float*          clsp  = (float*)(w2T + (size_t)768 * 3072); // 48*NC_*68 f32

  const int mt = (NROWS + 127) / 128; // 33

  // weight transpose+convert (f32 [K][N] -> bf16 [N][K])
  wtrans<<<dim3(2304 / 32, 768 / 32), 256, 0, stream>>>(qkv_w, wqkvT, 768, 2304);
  wtrans<<<dim3(768 / 32, 768 / 32), 256, 0, stream>>>(proj_w, wprojT, 768, 768);
  wtrans<<<dim3(3072 / 32, 768 / 32), 256, 0, stream>>>(mlp_w1, w1T, 768, 3072);
  wtrans<<<dim3(768 / 32, 3072 / 32), 256, 0, stream>>>(mlp_w2, w2T, 3072, 768);

  ln_bf16<<<NROWS, 256, 0, stream>>>(x, ln1_g, ln1_b, xn);
  gemm_mfma<0><<<dim3(2304 / 64, mt), 256, 0, stream>>>(
      xn, wqkvT, qkv_b, nullptr, qkv, NROWS, 2304, 768);
  attn_cls_part<<<B_ * H_ * NC_, 256, 0, stream>>>(qkv, clsp);
  attn_cls_merge<<<B_ * H_, 64, 0, stream>>>(clsp, attn);
  attn_patch<<<B_ * H_ * P_ / 4, 256, 0, stream>>>(qkv, routes, attn);
  gemm_mfma<1><<<dim3(768 / 64, mt), 256, 0, stream>>>(
      attn, wprojT, proj_b, x, x1, NROWS, 768, 768);
  ln_bf16<<<NROWS, 256, 0, stream>>>(x1, ln2_g, ln2_b, xn);
  gemm_mfma<2><<<dim3(3072 / 64, mt), 256, 0, stream>>>(
      xn, w1T, mlp_b1, nullptr, h1, NROWS, 3072, 768);
  gemm_mfma<1><<<dim3(768 / 64, mt), 256, 0, stream>>>(
      h1, w2T, mlp_b2, x1, outp, NROWS, 768, 3072);
}